// Round 3
// baseline (355.550 us; speedup 1.0000x reference)
//
#include <hip/hip_runtime.h>
#include <math.h>

// Problem constants: B=8, C=64, H=W=256, M1=M2=16.
#define NIMG 512          // B*C
#define HW   65536        // 256*256
// Workspace (floats): xf_re[131072] xf_im[131072] s_re[131072] s_im[131072]

// ---------------- Stage A ----------------
// One block per image (b,i), 512 threads: t = tid&255 (column w), s = tid>>8 (h-half).
// Phase 1 (radix-4 over h): partial C_s[u,t] = sum_{hb in [32s,32s+32)} over rows
//   {hb, hb+64, hb+128, hb+192}. Halves combined in LDS.
// Phase 2 (radix-4 over w, wb-half split + LDS reduce): Xf[u,v].
__global__ __launch_bounds__(512, 4)
void stageA(const float* __restrict__ x,
            float* __restrict__ xf_re, float* __restrict__ xf_im) {
    __shared__ __attribute__((aligned(16))) float tw[2048];   // [hb=64][k=16][2], 8 KB
    __shared__ __attribute__((aligned(16))) float cb[8192];   // [u=16][w=256] float2, 32 KB
    __shared__ __attribute__((aligned(16))) float cb2[8192];  // partial for s=1, 32 KB
    __shared__ __attribute__((aligned(16))) float rbuf[1024]; // [s=2][pair=256] float2, 4 KB
    const int tid = threadIdx.x;
    const int t = tid & 255, s = tid >> 8;
    const int img = blockIdx.x;

    // build twiddle table in LDS (2 entries/thread)
    #pragma unroll
    for (int i = tid; i < 1024; i += 512) {
        int n = i >> 4, k = i & 15;
        float sn, cs;
        sincospif(((k * n) & 255) * (1.0f / 128.0f), &sn, &cs);
        tw[2 * i] = cs; tw[2 * i + 1] = sn;
    }
    __syncthreads();

    const float* xp = x + (size_t)img * HW + t;
    float cr[16], ci[16];
    #pragma unroll
    for (int u = 0; u < 16; ++u) { cr[u] = 0.0f; ci[u] = 0.0f; }

    const float4* tw4 = (const float4*)tw;
    const int hb0 = s << 5;
    #pragma unroll 4
    for (int j = 0; j < 32; ++j) {
        const int hb = hb0 + j;
        float a = xp[hb * 256];
        float b = xp[(hb + 64) * 256];
        float c = xp[(hb + 128) * 256];
        float d = xp[(hb + 192) * 256];
        float p = a + c, m = a - c, q = b + d, r = b - d;
        float s0 = p + q, s2 = p - q;
        #pragma unroll
        for (int qq = 0; qq < 8; ++qq) {      // u = 2qq (even), 2qq+1 (odd)
            float4 e = tw4[hb * 8 + qq];      // uniform -> LDS broadcast b128
            float se = (qq & 1) ? s2 : s0;
            float si = (qq & 1) ? r : -r;
            cr[2*qq]     += se * e.x;
            ci[2*qq]     -= se * e.y;
            cr[2*qq + 1] += m  * e.z + si * e.w;
            ci[2*qq + 1] += si * e.z - m  * e.w;
        }
    }

    float2* cbv  = (float2*)cb;
    float2* cbv2 = (float2*)cb2;
    if (s) {
        #pragma unroll
        for (int u = 0; u < 16; ++u)
            cbv2[u * 256 + t] = make_float2(cr[u], ci[u]);
    }
    __syncthreads();
    if (!s) {
        #pragma unroll
        for (int u = 0; u < 16; ++u) {
            float2 o = cbv2[u * 256 + t];
            cbv[u * 256 + t] = make_float2(cr[u] + o.x, ci[u] + o.y);
        }
    }
    __syncthreads();

    // phase 2: pair p=(u,v), wb-half s
    const int u = t >> 4, v = t & 15;
    const bool odd = (v & 1) != 0;
    const float tsg = (v & 2) ? -1.0f : 1.0f;
    const float2* twc = (const float2*)tw;
    float xr = 0.0f, xi = 0.0f;
    const int wb0 = s << 5;
    #pragma unroll 2
    for (int j = 0; j < 32; ++j) {
        const int wb = wb0 + j;
        float2 Ca = cbv[u * 256 + wb];
        float2 Cb = cbv[u * 256 + wb + 64];
        float2 Cc = cbv[u * 256 + wb + 128];
        float2 Cd = cbv[u * 256 + wb + 192];
        float pr = Ca.x + Cc.x, pi_ = Ca.y + Cc.y;
        float mr = Ca.x - Cc.x, mi  = Ca.y - Cc.y;
        float qr = Cb.x + Cd.x, qi  = Cb.y + Cd.y;
        float rr = Cb.x - Cd.x, ri  = Cb.y - Cd.y;
        float X1 = odd ? mr : pr;
        float X2 = odd ? ri : qr;
        float Y1 = odd ? mi : pi_;
        float Y2 = odd ? -rr : qi;
        float sr = X1 + tsg * X2;
        float si = Y1 + tsg * Y2;
        float2 e = twc[wb * 16 + v];
        xr += sr * e.x + si * e.y;
        xi += si * e.x - sr * e.y;
    }
    float2* rb = (float2*)rbuf;
    rb[tid] = make_float2(xr, xi);
    __syncthreads();
    if (!s) {
        float2 o = rb[t + 256];
        xf_re[img * 256 + t] = xr + o.x;
        xf_im[img * 256 + t] = xi + o.y;
    }
}

// ---------------- Stage B ----------------
__global__ __launch_bounds__(256)
void stageB(const float* __restrict__ wr, const float* __restrict__ wi,
            const float* __restrict__ xf_re, const float* __restrict__ xf_im,
            float* __restrict__ s_re, float* __restrict__ s_im) {
    const int tid = threadIdx.x;
    const int o = blockIdx.x >> 3;
    const int b = blockIdx.x & 7;
    float sr = 0.0f, si = 0.0f;
    #pragma unroll 8
    for (int i = 0; i < 64; ++i) {
        float wre = wr[((i * 64 + o) << 8) + tid];
        float wim = wi[((i * 64 + o) << 8) + tid];
        float xr  = xf_re[((b * 64 + i) << 8) + tid];
        float xi  = xf_im[((b * 64 + i) << 8) + tid];
        sr += xr * wre - xi * wim;
        si += xr * wim + xi * wre;
    }
    s_re[((b * 64 + o) << 8) + tid] = sr;
    s_im[((b * 64 + o) << 8) + tid] = si;
}

// ---------------- Stage C ----------------
// Block = (img, s): s picks hb in [32s, 32s+32). Thread t = column w.
// Phase 1: T[u,t] = sum_v (c_v/65536) S[u,v] e^{+2pi i v t/256}  (register rotation)
// Phase 2 (radix-4 over h): rows {hb, hb+64, hb+128, hb+192}.
__global__ __launch_bounds__(256, 4)
void stageC(const float* __restrict__ s_re, const float* __restrict__ s_im,
            float* __restrict__ out) {
    __shared__ __attribute__((aligned(16))) float tw[2048];  // 8 KB
    __shared__ __attribute__((aligned(16))) float sl[512];   // [u][v][2], pre-scaled
    const int tid = threadIdx.x;
    const int img = blockIdx.x >> 1;
    const int s   = blockIdx.x & 1;

    #pragma unroll
    for (int i = tid; i < 1024; i += 256) {
        int n = i >> 4, k = i & 15;
        float sn, cs;
        sincospif(((k * n) & 255) * (1.0f / 128.0f), &sn, &cs);
        tw[2 * i] = cs; tw[2 * i + 1] = sn;
    }
    {
        int v = tid & 15;
        float scale = (v == 0 ? 1.0f : 2.0f) * (1.0f / 65536.0f);
        sl[tid * 2]     = s_re[img * 256 + tid] * scale;
        sl[tid * 2 + 1] = s_im[img * 256 + tid] * scale;
    }
    __syncthreads();

    float tr[16], ti[16];
    #pragma unroll
    for (int u = 0; u < 16; ++u) { tr[u] = 0.0f; ti[u] = 0.0f; }

    float bs, bc;
    sincospif(tid * (1.0f / 128.0f), &bs, &bc);   // e^{+2pi i w/256}
    float ec = 1.0f, es = 0.0f;
    for (int v = 0; v < 16; ++v) {
        #pragma unroll
        for (int u = 0; u < 16; ++u) {
            float a = sl[(u * 16 + v) * 2];       // uniform -> broadcast
            float b = sl[(u * 16 + v) * 2 + 1];
            tr[u] += a * ec - b * es;
            ti[u] += a * es + b * ec;
        }
        float nc = ec * bc - es * bs;
        float ns = ec * bs + es * bc;
        ec = nc; es = ns;
    }

    float* op = out + (size_t)img * HW + tid;
    const float4* tw4 = (const float4*)tw;
    const int hb0 = s << 5;
    #pragma unroll 2
    for (int j = 0; j < 32; ++j) {
        const int hb = hb0 + j;
        float o0 = 0.f, o1 = 0.f, o2 = 0.f, o3 = 0.f;
        #pragma unroll
        for (int qq = 0; qq < 8; ++qq) {          // u = 2qq, 2qq+1
            float4 e = tw4[hb * 8 + qq];          // uniform broadcast
            float pre = tr[2*qq]   * e.x - ti[2*qq]   * e.y;
            float pro = tr[2*qq+1] * e.z - ti[2*qq+1] * e.w;
            float pio = tr[2*qq+1] * e.w + ti[2*qq+1] * e.z;
            o0 += pre + pro;
            o2 += pre - pro;
            float g1 = pre - pio, g3 = pre + pio;
            if (qq & 1) { o1 -= g1; o3 -= g3; }
            else        { o1 += g1; o3 += g3; }
        }
        op[hb * 256]         = o0;
        op[(hb + 64) * 256]  = o1;
        op[(hb + 128) * 256] = o2;
        op[(hb + 192) * 256] = o3;
    }
}

extern "C" void kernel_launch(void* const* d_in, const int* in_sizes, int n_in,
                              void* d_out, int out_size, void* d_ws, size_t ws_size,
                              hipStream_t stream) {
    const float* x  = (const float*)d_in[0];
    const float* wr = (const float*)d_in[1];
    const float* wi = (const float*)d_in[2];
    float* out = (float*)d_out;
    float* ws  = (float*)d_ws;

    float* xf_re = ws;
    float* xf_im = ws + 131072;
    float* s_re  = ws + 262144;
    float* s_im  = ws + 393216;

    stageA<<<NIMG, 512, 0, stream>>>(x, xf_re, xf_im);
    stageB<<<NIMG, 256, 0, stream>>>(wr, wi, xf_re, xf_im, s_re, s_im);
    stageC<<<NIMG * 2, 256, 0, stream>>>(s_re, s_im, out);
}

// Round 4
// 302.042 us; speedup vs baseline: 1.1772x; 1.1772x over previous
//
#include <hip/hip_runtime.h>
#include <math.h>

// Problem constants: B=8, C=64, H=W=256, M1=M2=16.
#define NIMG 512          // B*C
#define HW   65536        // 256*256
// Workspace (floats): xf_re[131072] xf_im[131072] s_re[131072] s_im[131072]

// ---------------- Stage A ----------------
// One block per image (b,i), 256 threads, thread t = column w.
// Phase 1 (radix-4 over h): C[u,t] = sum_h x[h,t] e^{-2pi i u h/256}; rows
//   {hb, hb+64, hb+128, hb+192} share twiddle tw[u,hb] with factors (-i)^u.
//   Loads hand-batched 16-at-a-time for ILP latency hiding (8 waves/CU only).
// Phase 2 (radix-4 over w): Xf[u,v], thread t -> (u=t>>4, v=t&15).
// launch_bounds(256,2): VGPR cap 256 — do NOT tighten, (512,4) caused 234 MB
// of scratch spills in round 3 (VGPR capped at 64 vs ~90 live).
__global__ __launch_bounds__(256, 2)
void stageA(const float* __restrict__ x,
            float* __restrict__ xf_re, float* __restrict__ xf_im) {
    __shared__ __attribute__((aligned(16))) float tw[2048];   // [hb=64][k=16][2], 8 KB
    __shared__ __attribute__((aligned(16))) float cbuf[8192]; // [u=16][w=256] float2, 32 KB
    const int tid = threadIdx.x;
    const int img = blockIdx.x;

    #pragma unroll
    for (int i = tid; i < 1024; i += 256) {
        int n = i >> 4, k = i & 15;
        float sn, cs;
        sincospif(((k * n) & 255) * (1.0f / 128.0f), &sn, &cs);
        tw[2 * i] = cs; tw[2 * i + 1] = sn;
    }
    __syncthreads();

    const float* xp = x + (size_t)img * HW + tid;
    float cr[16], ci[16];
    #pragma unroll
    for (int u = 0; u < 16; ++u) { cr[u] = 0.0f; ci[u] = 0.0f; }

    const float4* tw4 = (const float4*)tw;
    #pragma unroll 2
    for (int hb = 0; hb < 64; hb += 4) {
        // batch 16 independent global loads first (ILP: ~32 loads in flight w/ unroll 2)
        float a[4], b[4], c[4], d[4];
        #pragma unroll
        for (int j = 0; j < 4; ++j) {
            a[j] = xp[(hb + j) * 256];
            b[j] = xp[(hb + j + 64) * 256];
            c[j] = xp[(hb + j + 128) * 256];
            d[j] = xp[(hb + j + 192) * 256];
        }
        #pragma unroll
        for (int j = 0; j < 4; ++j) {
            float p = a[j] + c[j], m = a[j] - c[j];
            float q = b[j] + d[j], r = b[j] - d[j];
            float s0 = p + q, s2 = p - q;
            #pragma unroll
            for (int qq = 0; qq < 8; ++qq) {      // u = 2qq (even), 2qq+1 (odd)
                float4 e = tw4[(hb + j) * 8 + qq]; // uniform -> LDS broadcast b128
                float se = (qq & 1) ? s2 : s0;     // folds statically after unroll
                float si = (qq & 1) ? r : -r;
                cr[2*qq]     += se * e.x;
                ci[2*qq]     -= se * e.y;
                cr[2*qq + 1] += m  * e.z + si * e.w;
                ci[2*qq + 1] += si * e.z - m  * e.w;
            }
        }
    }

    float2* cb = (float2*)cbuf;               // [u*256 + w]: lane-stride 8B, bank-clean
    #pragma unroll
    for (int u = 0; u < 16; ++u)
        cb[u * 256 + tid] = make_float2(cr[u], ci[u]);
    __syncthreads();

    const int u = tid >> 4, v = tid & 15;
    const bool odd = (v & 1) != 0;
    const float tsg = (v & 2) ? -1.0f : 1.0f;
    const float2* twc = (const float2*)tw;
    float xr = 0.0f, xi = 0.0f;
    #pragma unroll 2
    for (int wb = 0; wb < 64; ++wb) {
        float2 Ca = cb[u * 256 + wb];         // 4-addr broadcasts
        float2 Cb = cb[u * 256 + wb + 64];
        float2 Cc = cb[u * 256 + wb + 128];
        float2 Cd = cb[u * 256 + wb + 192];
        float pr = Ca.x + Cc.x, pi_ = Ca.y + Cc.y;
        float mr = Ca.x - Cc.x, mi  = Ca.y - Cc.y;
        float qr = Cb.x + Cd.x, qi  = Cb.y + Cd.y;
        float rr = Cb.x - Cd.x, ri  = Cb.y - Cd.y;
        float X1 = odd ? mr : pr;
        float X2 = odd ? ri : qr;
        float Y1 = odd ? mi : pi_;
        float Y2 = odd ? -rr : qi;
        float sr = X1 + tsg * X2;
        float si = Y1 + tsg * Y2;
        float2 e = twc[wb * 16 + v];          // per-lane v, clean banks
        xr += sr * e.x + si * e.y;            // s * (cos - i sin)
        xi += si * e.x - sr * e.y;
    }
    xf_re[img * 256 + tid] = xr;
    xf_im[img * 256 + tid] = xi;
}

// ---------------- Stage B ----------------
__global__ __launch_bounds__(256)
void stageB(const float* __restrict__ wr, const float* __restrict__ wi,
            const float* __restrict__ xf_re, const float* __restrict__ xf_im,
            float* __restrict__ s_re, float* __restrict__ s_im) {
    const int tid = threadIdx.x;
    const int o = blockIdx.x >> 3;
    const int b = blockIdx.x & 7;
    float sr = 0.0f, si = 0.0f;
    #pragma unroll 8
    for (int i = 0; i < 64; ++i) {
        float wre = wr[((i * 64 + o) << 8) + tid];
        float wim = wi[((i * 64 + o) << 8) + tid];
        float xr  = xf_re[((b * 64 + i) << 8) + tid];
        float xi  = xf_im[((b * 64 + i) << 8) + tid];
        sr += xr * wre - xi * wim;
        si += xr * wim + xi * wre;
    }
    s_re[((b * 64 + o) << 8) + tid] = sr;
    s_im[((b * 64 + o) << 8) + tid] = si;
}

// ---------------- Stage C ----------------
// Block = (img, s): s picks hb in [32s, 32s+32). Thread t = column w.
// Grid 1024 -> 4 blocks/CU (16 waves) for store-side latency hiding.
__global__ __launch_bounds__(256, 4)
void stageC(const float* __restrict__ s_re, const float* __restrict__ s_im,
            float* __restrict__ out) {
    __shared__ __attribute__((aligned(16))) float tw[2048];  // 8 KB
    __shared__ __attribute__((aligned(16))) float sl[512];   // [u][v][2], pre-scaled
    const int tid = threadIdx.x;
    const int img = blockIdx.x >> 1;
    const int s   = blockIdx.x & 1;

    #pragma unroll
    for (int i = tid; i < 1024; i += 256) {
        int n = i >> 4, k = i & 15;
        float sn, cs;
        sincospif(((k * n) & 255) * (1.0f / 128.0f), &sn, &cs);
        tw[2 * i] = cs; tw[2 * i + 1] = sn;
    }
    {
        int v = tid & 15;
        float scale = (v == 0 ? 1.0f : 2.0f) * (1.0f / 65536.0f);
        sl[tid * 2]     = s_re[img * 256 + tid] * scale;
        sl[tid * 2 + 1] = s_im[img * 256 + tid] * scale;
    }
    __syncthreads();

    float tr[16], ti[16];
    #pragma unroll
    for (int u = 0; u < 16; ++u) { tr[u] = 0.0f; ti[u] = 0.0f; }

    float bs, bc;
    sincospif(tid * (1.0f / 128.0f), &bs, &bc);   // e^{+2pi i w/256}
    float ec = 1.0f, es = 0.0f;
    for (int v = 0; v < 16; ++v) {
        #pragma unroll
        for (int u = 0; u < 16; ++u) {
            float a = sl[(u * 16 + v) * 2];       // uniform -> broadcast
            float b = sl[(u * 16 + v) * 2 + 1];
            tr[u] += a * ec - b * es;
            ti[u] += a * es + b * ec;
        }
        float nc = ec * bc - es * bs;
        float ns = ec * bs + es * bc;
        ec = nc; es = ns;
    }

    float* op = out + (size_t)img * HW + tid;
    const float4* tw4 = (const float4*)tw;
    const int hb0 = s << 5;
    #pragma unroll 2
    for (int j = 0; j < 32; ++j) {
        const int hb = hb0 + j;
        float o0 = 0.f, o1 = 0.f, o2 = 0.f, o3 = 0.f;
        #pragma unroll
        for (int qq = 0; qq < 8; ++qq) {          // u = 2qq, 2qq+1
            float4 e = tw4[hb * 8 + qq];          // uniform broadcast
            float pre = tr[2*qq]   * e.x - ti[2*qq]   * e.y;
            float pro = tr[2*qq+1] * e.z - ti[2*qq+1] * e.w;
            float pio = tr[2*qq+1] * e.w + ti[2*qq+1] * e.z;
            o0 += pre + pro;
            o2 += pre - pro;
            float g1 = pre - pio, g3 = pre + pio;
            if (qq & 1) { o1 -= g1; o3 -= g3; }
            else        { o1 += g1; o3 += g3; }
        }
        op[hb * 256]         = o0;
        op[(hb + 64) * 256]  = o1;
        op[(hb + 128) * 256] = o2;
        op[(hb + 192) * 256] = o3;
    }
}

extern "C" void kernel_launch(void* const* d_in, const int* in_sizes, int n_in,
                              void* d_out, int out_size, void* d_ws, size_t ws_size,
                              hipStream_t stream) {
    const float* x  = (const float*)d_in[0];
    const float* wr = (const float*)d_in[1];
    const float* wi = (const float*)d_in[2];
    float* out = (float*)d_out;
    float* ws  = (float*)d_ws;

    float* xf_re = ws;
    float* xf_im = ws + 131072;
    float* s_re  = ws + 262144;
    float* s_im  = ws + 393216;

    stageA<<<NIMG, 256, 0, stream>>>(x, xf_re, xf_im);
    stageB<<<NIMG, 256, 0, stream>>>(wr, wi, xf_re, xf_im, s_re, s_im);
    stageC<<<NIMG * 2, 256, 0, stream>>>(s_re, s_im, out);
}